// Round 1
// baseline (335.737 us; speedup 1.0000x reference)
//
#include <hip/hip_runtime.h>

// ImageAugmentation: B=256, C=3, H=W=224, fp32.
// Structure:
//   memsetAsync(ws)  -> zero per-image gray-sum accumulators
//   kernel gray_mean -> per-image sum of grayscale(clip(bf*img,0,1)), atomicAdd per block
//   kernel aug_main  -> fused jitter (+4x jitter-on-gather for crop path) + bilinear resize
// Per-image branches (jitter_on / crop_on) are uniform per block (blockIdx.y = image).
// floor()-critical crop params computed with fp contract(off) to match f32 reference exactly.

static constexpr int   kB     = 256;
static constexpr int   kHW    = 224;
static constexpr int   kNPix  = kHW * kHW;   // 50176
static constexpr int   kPlane = kNPix;
static constexpr float kPJitter = 0.8f;
static constexpr float kPCrop   = 0.5f;

__device__ __forceinline__ float clamp01(float x) {
    return fminf(fmaxf(x, 0.0f), 1.0f);
}

__device__ __forceinline__ float fast_rcp(float x) {
#if __has_builtin(__builtin_amdgcn_rcpf)
    return __builtin_amdgcn_rcpf(x);   // ~1 ulp approx; effect is continuous, OK at 2e-2 abs tol
#else
    return 1.0f / x;
#endif
}

struct Px { float r, g, b; };

// Full color-jitter chain for one pixel. oc = (1-cf)*mean_gray precomputed per image.
__device__ __forceinline__ Px jitter_px(Px p, float bf, float cf, float sf,
                                        float hf, float oc) {
    // brightness: clip(bf * x, 0, 1)
    float r = clamp01(bf * p.r);
    float g = clamp01(bf * p.g);
    float b = clamp01(bf * p.b);
    // contrast: clip(cf*x + (1-cf)*mean_gray, 0, 1)
    r = clamp01(cf * r + oc);
    g = clamp01(cf * g + oc);
    b = clamp01(cf * b + oc);
    // saturation: clip(sf*x + (1-sf)*gray(x), 0, 1)
    float gray = 0.299f * r + 0.587f * g + 0.114f * b;
    float os = (1.0f - sf) * gray;
    r = clamp01(sf * r + os);
    g = clamp01(sf * g + os);
    b = clamp01(sf * b + os);
    // hue: RGB -> H(SV) -> shift -> RGB  (matches reference branch priority r,g,b)
    float maxc = fmaxf(fmaxf(r, g), b);
    float minc = fminf(fminf(r, g), b);
    float v  = maxc;
    float cr = maxc - minc;
    bool  eqc = (cr == 0.0f);
    float s   = eqc ? 0.0f : cr * fast_rcp(maxc);
    float inv = eqc ? 1.0f : fast_rcp(cr);
    float rc = (maxc - r) * inv;
    float gc = (maxc - g) * inv;
    float bc = (maxc - b) * inv;
    float h = (maxc == r) ? (bc - gc)
            : (maxc == g) ? (2.0f + rc - bc)
                          : (4.0f + gc - rc);
    h = h * 0.16666667f + 1.0f;
    h = h - floorf(h);          // mod(h/6+1, 1)
    h = h + hf;
    h = h - floorf(h);          // mod(h+hue, 1)
    float h6 = h * 6.0f;
    float fi = floorf(h6);
    float f  = h6 - fi;
    int   i  = ((int)fi) % 6;   // h6 can hit 6.0 exactly -> i=0, f=0 (matches ref)
    float pp = v * (1.0f - s);
    float qq = v * (1.0f - s * f);
    float tt = v * (1.0f - s * (1.0f - f));
    float r2 = (i == 1) ? qq : ((i == 2) || (i == 3)) ? pp : (i == 4) ? tt : v;
    float g2 = (i == 0) ? tt : ((i == 1) || (i == 2)) ? v  : (i == 3) ? qq : pp;
    float b2 = ((i == 0) || (i == 1)) ? pp : (i == 2) ? tt : (i == 5) ? qq : v;
    Px o;
    o.r = clamp01(r2);
    o.g = clamp01(g2);
    o.b = clamp01(b2);
    return o;
}

// Kernel A: per-image sum of grayscale(brightness(img)). 8 blocks x 256 threads per image.
__global__ __launch_bounds__(256)
void gray_mean_kernel(const float* __restrict__ img,
                      const float* __restrict__ u_jitter,
                      const float* __restrict__ u_bright,
                      float* __restrict__ gray_sum)
{
    const int b = blockIdx.y;
    if (u_jitter[b] >= kPJitter) return;   // mean unused for jitter-off images
    const float bf = 1.0f + (2.0f * u_bright[b] - 1.0f) * 0.2f;
    const float* base = img + (size_t)b * 3 * kPlane;
    const int t = blockIdx.x * 256 + threadIdx.x;   // 0..2047
    float acc = 0.0f;
    for (int p = t; p < kNPix; p += 2048) {
        float r  = clamp01(bf * base[p]);
        float g  = clamp01(bf * base[p + kPlane]);
        float bl = clamp01(bf * base[p + 2 * kPlane]);
        acc += 0.299f * r + 0.587f * g + 0.114f * bl;
    }
#pragma unroll
    for (int off = 32; off > 0; off >>= 1)
        acc += __shfl_down(acc, off);
    __shared__ float red[4];
    const int lane = threadIdx.x & 63;
    const int w    = threadIdx.x >> 6;
    if (lane == 0) red[w] = acc;
    __syncthreads();
    if (threadIdx.x == 0)
        atomicAdd(&gray_sum[b], red[0] + red[1] + red[2] + red[3]);
}

// Kernel B: one thread per output pixel (all 3 channels).
__global__ __launch_bounds__(256)
void aug_main_kernel(const float* __restrict__ img,
                     const float* __restrict__ u_jitter,
                     const float* __restrict__ u_bright,
                     const float* __restrict__ u_contrast,
                     const float* __restrict__ u_sat,
                     const float* __restrict__ u_hue,
                     const float* __restrict__ u_crop,
                     const float* __restrict__ u_scale,
                     const float* __restrict__ u_top,
                     const float* __restrict__ u_left,
                     const float* __restrict__ gray_sum,
                     float* __restrict__ out)
{
    const int b   = blockIdx.y;
    const int pix = blockIdx.x * 256 + threadIdx.x;   // 196*256 == 50176 exactly
    const int oy  = pix / kHW;
    const int ox  = pix - oy * kHW;

    const bool jitter_on = u_jitter[b] < kPJitter;
    const bool crop_on   = u_crop[b]   < kPCrop;

    float bf = 1.0f, cf = 1.0f, sf = 1.0f, hf = 0.0f, oc = 0.0f;
    if (jitter_on) {
        bf = 1.0f + (2.0f * u_bright[b]   - 1.0f) * 0.2f;
        cf = 1.0f + (2.0f * u_contrast[b] - 1.0f) * 0.2f;
        sf = 1.0f + (2.0f * u_sat[b]      - 1.0f) * 0.2f;
        hf = (2.0f * u_hue[b] - 1.0f) * 0.05f;
        const float mg = gray_sum[b] * (1.0f / (float)kNPix);
        oc = (1.0f - cf) * mg;
    }

    const float* base = img + (size_t)b * 3 * kPlane;
    float outr, outg, outb;

    if (crop_on) {
        float top, left, ch;
        {
#pragma clang fp contract(off)
            // floor() cliffs: must match reference f32 op-for-op (no fma contraction)
            float scale = 0.85f + 0.15f * u_scale[b];
            ch = floorf(224.0f * scale);            // cw == ch (H == W)
            float rem = (224.0f - ch) + 1.0f;
            top  = fminf(fmaxf(floorf(u_top[b]  * rem), 0.0f), 224.0f - ch);
            left = fminf(fmaxf(floorf(u_left[b] * rem), 0.0f), 224.0f - ch);
        }
        float fy, fx;
        {
#pragma clang fp contract(off)
            fy = top  + ((float)oy + 0.5f) * ch / 224.0f - 0.5f;
            fx = left + ((float)ox + 0.5f) * ch / 224.0f - 0.5f;
        }
        fy = fminf(fmaxf(fy, 0.0f), 223.0f);
        fx = fminf(fmaxf(fx, 0.0f), 223.0f);
        float y0f = floorf(fy), x0f = floorf(fx);
        float wy = fy - y0f,   wx = fx - x0f;
        int y0 = (int)y0f, x0 = (int)x0f;
        int y1 = min(y0 + 1, kHW - 1), x1 = min(x0 + 1, kHW - 1);

        int idx[4] = { y0 * kHW + x0, y0 * kHW + x1,
                       y1 * kHW + x0, y1 * kHW + x1 };
        Px px[4];
#pragma unroll
        for (int j = 0; j < 4; ++j) {
            Px p;
            p.r = base[idx[j]];
            p.g = base[idx[j] + kPlane];
            p.b = base[idx[j] + 2 * kPlane];
            px[j] = jitter_on ? jitter_px(p, bf, cf, sf, hf, oc) : p;
        }
        float r0 = (1.0f - wx) * px[0].r + wx * px[1].r;
        float r1 = (1.0f - wx) * px[2].r + wx * px[3].r;
        outr = (1.0f - wy) * r0 + wy * r1;
        float g0 = (1.0f - wx) * px[0].g + wx * px[1].g;
        float g1 = (1.0f - wx) * px[2].g + wx * px[3].g;
        outg = (1.0f - wy) * g0 + wy * g1;
        float b0 = (1.0f - wx) * px[0].b + wx * px[1].b;
        float b1 = (1.0f - wx) * px[2].b + wx * px[3].b;
        outb = (1.0f - wy) * b0 + wy * b1;
    } else {
        const int idx = oy * kHW + ox;
        Px p;
        p.r = base[idx];
        p.g = base[idx + kPlane];
        p.b = base[idx + 2 * kPlane];
        if (jitter_on) p = jitter_px(p, bf, cf, sf, hf, oc);
        outr = p.r; outg = p.g; outb = p.b;
    }

    const size_t o = (size_t)b * 3 * kPlane + (size_t)oy * kHW + ox;
    out[o]              = outr;
    out[o + kPlane]     = outg;
    out[o + 2 * kPlane] = outb;
}

extern "C" void kernel_launch(void* const* d_in, const int* in_sizes, int n_in,
                              void* d_out, int out_size, void* d_ws, size_t ws_size,
                              hipStream_t stream) {
    const float* img = (const float*)d_in[0];
    const float* uj  = (const float*)d_in[1];
    const float* ub  = (const float*)d_in[2];
    const float* uc  = (const float*)d_in[3];
    const float* us  = (const float*)d_in[4];
    const float* uh  = (const float*)d_in[5];
    const float* ucr = (const float*)d_in[6];
    const float* usc = (const float*)d_in[7];
    const float* ut  = (const float*)d_in[8];
    const float* ul  = (const float*)d_in[9];
    float* gray_sum  = (float*)d_ws;      // 256 floats
    float* out       = (float*)d_out;

    hipMemsetAsync(gray_sum, 0, kB * sizeof(float), stream);

    dim3 gridA(8, kB, 1);
    gray_mean_kernel<<<gridA, 256, 0, stream>>>(img, uj, ub, gray_sum);

    dim3 gridB(kNPix / 256, kB, 1);
    aug_main_kernel<<<gridB, 256, 0, stream>>>(img, uj, ub, uc, us, uh,
                                               ucr, usc, ut, ul, gray_sum, out);
}

// Round 2
// 308.234 us; speedup vs baseline: 1.0892x; 1.0892x over previous
//
#include <hip/hip_runtime.h>

// ImageAugmentation: B=256, C=3, H=W=224, fp32.
// R2 structure:
//   gray_mean: 1 block (1024 thr) per image, float4 loads, no atomics/memset.
//   aug_main : 1 block (256 thr) per 4 output rows of one image.
//     crop-on : stage 5 jittered source rows in LDS (jitter ONCE per source px,
//               1.25x/output instead of 4x/output), bilinear from LDS.
//     crop-off: float4 load -> jitter -> float4 store.
// Branches (jitter_on/crop_on) are uniform per block (blockIdx.y = image).
// floor() cliffs (crop params, fy/fx) computed with fp contract(off) to match
// the f32 reference op-for-op.

static constexpr int   kB      = 256;
static constexpr int   kHW     = 224;
static constexpr int   kNPix   = kHW * kHW;    // 50176
static constexpr int   kPlane  = kNPix;
static constexpr int   kPlane4 = kNPix / 4;    // 12544

__device__ __forceinline__ float clamp01(float x) {
    return fminf(fmaxf(x, 0.0f), 1.0f);
}

__device__ __forceinline__ float fast_rcp(float x) {
#if __has_builtin(__builtin_amdgcn_rcpf)
    return __builtin_amdgcn_rcpf(x);   // ~1 ulp; continuous effect, fine at 2e-2 tol
#else
    return 1.0f / x;
#endif
}

struct Px { float r, g, b; };

// Full color-jitter chain for one pixel. oc = (1-cf)*mean_gray per image.
__device__ __forceinline__ Px jitter_px(Px p, float bf, float cf, float sf,
                                        float hf, float oc) {
    float r = clamp01(bf * p.r);
    float g = clamp01(bf * p.g);
    float b = clamp01(bf * p.b);
    r = clamp01(cf * r + oc);
    g = clamp01(cf * g + oc);
    b = clamp01(cf * b + oc);
    float gray = 0.299f * r + 0.587f * g + 0.114f * b;
    float os = (1.0f - sf) * gray;
    r = clamp01(sf * r + os);
    g = clamp01(sf * g + os);
    b = clamp01(sf * b + os);
    float maxc = fmaxf(fmaxf(r, g), b);
    float minc = fminf(fminf(r, g), b);
    float v  = maxc;
    float cr = maxc - minc;
    bool  eqc = (cr == 0.0f);
    float s   = eqc ? 0.0f : cr * fast_rcp(maxc);
    float inv = eqc ? 1.0f : fast_rcp(cr);
    float rc = (maxc - r) * inv;
    float gc = (maxc - g) * inv;
    float bc = (maxc - b) * inv;
    float h = (maxc == r) ? (bc - gc)
            : (maxc == g) ? (2.0f + rc - bc)
                          : (4.0f + gc - rc);
    h = h * 0.16666667f + 1.0f;
    h = h - floorf(h);
    h = h + hf;
    h = h - floorf(h);
    float h6 = h * 6.0f;
    float fi = floorf(h6);
    float f  = h6 - fi;
    int   i  = ((int)fi) % 6;   // h6 in [0,6]; ==6 -> i=0,f=0 (matches ref)
    float pp = v * (1.0f - s);
    float qq = v * (1.0f - s * f);
    float tt = v * (1.0f - s * (1.0f - f));
    float r2 = (i == 1) ? qq : ((i == 2) || (i == 3)) ? pp : (i == 4) ? tt : v;
    float g2 = (i == 0) ? tt : ((i == 1) || (i == 2)) ? v  : (i == 3) ? qq : pp;
    float b2 = ((i == 0) || (i == 1)) ? pp : (i == 2) ? tt : (i == 5) ? qq : v;
    Px o;
    o.r = clamp01(r2);
    o.g = clamp01(g2);
    o.b = clamp01(b2);
    return o;
}

// Kernel A: per-image mean of grayscale(brightness(img)).
// One 1024-thread block per image; float4 loads; plain store (no atomics).
__global__ __launch_bounds__(1024)
void gray_mean_kernel(const float* __restrict__ img,
                      const float* __restrict__ u_jitter,
                      const float* __restrict__ u_bright,
                      float* __restrict__ gray_sum)
{
    const int b = blockIdx.x;
    if (u_jitter[b] >= 0.8f) return;   // mean unused for jitter-off images
    const float bf = 1.0f + (2.0f * u_bright[b] - 1.0f) * 0.2f;
    const float4* pr = (const float4*)(img + (size_t)b * 3 * kPlane);
    const float4* pg = pr + kPlane4;
    const float4* pb = pr + 2 * kPlane4;
    float acc = 0.0f;
    for (int i = threadIdx.x; i < kPlane4; i += 1024) {
        float4 r = pr[i], g = pg[i], bl = pb[i];
        acc += 0.299f * clamp01(bf * r.x) + 0.587f * clamp01(bf * g.x) + 0.114f * clamp01(bf * bl.x);
        acc += 0.299f * clamp01(bf * r.y) + 0.587f * clamp01(bf * g.y) + 0.114f * clamp01(bf * bl.y);
        acc += 0.299f * clamp01(bf * r.z) + 0.587f * clamp01(bf * g.z) + 0.114f * clamp01(bf * bl.z);
        acc += 0.299f * clamp01(bf * r.w) + 0.587f * clamp01(bf * g.w) + 0.114f * clamp01(bf * bl.w);
    }
#pragma unroll
    for (int off = 32; off > 0; off >>= 1)
        acc += __shfl_down(acc, off);
    __shared__ float red[16];
    const int lane = threadIdx.x & 63;
    const int w    = threadIdx.x >> 6;
    if (lane == 0) red[w] = acc;
    __syncthreads();
    if (threadIdx.x == 0) {
        float s = 0.0f;
#pragma unroll
        for (int k = 0; k < 16; ++k) s += red[k];
        gray_sum[b] = s;
    }
}

// Kernel B: one block = 4 output rows of one image.
__global__ __launch_bounds__(256)
void aug_main_kernel(const float* __restrict__ img,
                     const float* __restrict__ u_jitter,
                     const float* __restrict__ u_bright,
                     const float* __restrict__ u_contrast,
                     const float* __restrict__ u_sat,
                     const float* __restrict__ u_hue,
                     const float* __restrict__ u_crop,
                     const float* __restrict__ u_scale,
                     const float* __restrict__ u_top,
                     const float* __restrict__ u_left,
                     const float* __restrict__ gray_sum,
                     float* __restrict__ out)
{
    const int b   = blockIdx.y;
    const int oy0 = blockIdx.x * 4;
    const int t   = threadIdx.x;

    const bool jitter_on = u_jitter[b] < 0.8f;
    const bool crop_on   = u_crop[b]   < 0.5f;

    float bf = 1.0f, cf = 1.0f, sf = 1.0f, hf = 0.0f, oc = 0.0f;
    if (jitter_on) {
        bf = 1.0f + (2.0f * u_bright[b]   - 1.0f) * 0.2f;
        cf = 1.0f + (2.0f * u_contrast[b] - 1.0f) * 0.2f;
        sf = 1.0f + (2.0f * u_sat[b]      - 1.0f) * 0.2f;
        hf = (2.0f * u_hue[b] - 1.0f) * 0.05f;
        const float mg = gray_sum[b] * (1.0f / (float)kNPix);
        oc = (1.0f - cf) * mg;
    }

    const float* base  = img + (size_t)b * 3 * kPlane;
    float*       obase = out + (size_t)b * 3 * kPlane;

    if (!crop_on) {
        // 4 rows = 896 px = 224 float4 per plane; threads 0..223 active.
        if (t < 224) {
            const int f4 = oy0 * (kHW / 4) + t;
            const float4* p4 = (const float4*)base;
            float4 r4 = p4[f4];
            float4 g4 = p4[f4 + kPlane4];
            float4 b4 = p4[f4 + 2 * kPlane4];
            if (jitter_on) {
                Px a0 = jitter_px({r4.x, g4.x, b4.x}, bf, cf, sf, hf, oc);
                Px a1 = jitter_px({r4.y, g4.y, b4.y}, bf, cf, sf, hf, oc);
                Px a2 = jitter_px({r4.z, g4.z, b4.z}, bf, cf, sf, hf, oc);
                Px a3 = jitter_px({r4.w, g4.w, b4.w}, bf, cf, sf, hf, oc);
                r4 = {a0.r, a1.r, a2.r, a3.r};
                g4 = {a0.g, a1.g, a2.g, a3.g};
                b4 = {a0.b, a1.b, a2.b, a3.b};
            }
            float4* o4 = (float4*)obase;
            o4[f4]               = r4;
            o4[f4 + kPlane4]     = g4;
            o4[f4 + 2 * kPlane4] = b4;
        }
        return;
    }

    // ---- crop path ----
    float ch, top, left;
    {
#pragma clang fp contract(off)
        // floor() cliffs must match reference f32 op-for-op (no fma contraction)
        float scale = 0.85f + 0.15f * u_scale[b];
        ch = floorf(224.0f * scale);             // cw == ch (H == W)
        float rem = (224.0f - ch) + 1.0f;
        top  = fminf(fmaxf(floorf(u_top[b]  * rem), 0.0f), 224.0f - ch);
        left = fminf(fmaxf(floorf(u_left[b] * rem), 0.0f), 224.0f - ch);
    }

    // Block-uniform LDS row-window base: rows [ybase, ybase+4] cover all taps
    // of output rows oy0..oy0+3 (source step ch/224 <= 1).
    int ybase;
    {
#pragma clang fp contract(off)
        float fy0 = top + ((float)oy0 + 0.5f) * ch / 224.0f - 0.5f;
        fy0 = fminf(fmaxf(fy0, 0.0f), 223.0f);
        ybase = (int)floorf(fy0);
    }
    ybase = min(ybase, kHW - 5);   // ensure ybase+4 <= 223

    __shared__ float sm[3][5 * kHW];   // 13.1 KB

    // Stage + jitter 5 source rows (1120 px), ONE jitter chain per source px.
    for (int p = t; p < 5 * kHW; p += 256) {
        const int r   = p / kHW;
        const int col = p - r * kHW;
        const int gi  = (ybase + r) * kHW + col;
        Px q;
        q.r = base[gi];
        q.g = base[gi + kPlane];
        q.b = base[gi + 2 * kPlane];
        if (jitter_on) q = jitter_px(q, bf, cf, sf, hf, oc);
        sm[0][p] = q.r;
        sm[1][p] = q.g;
        sm[2][p] = q.b;
    }
    __syncthreads();

    // 896 outputs; bilinear from LDS. Lanes read near-consecutive cols
    // (<=2-way bank aliasing: free).
    for (int o = t; o < 4 * kHW; o += 256) {
        const int dy = o / kHW;          // 0..3
        const int ox = o - dy * kHW;
        const int oy = oy0 + dy;
        float fy, fx;
        {
#pragma clang fp contract(off)
            fy = top  + ((float)oy + 0.5f) * ch / 224.0f - 0.5f;
            fx = left + ((float)ox + 0.5f) * ch / 224.0f - 0.5f;
        }
        fy = fminf(fmaxf(fy, 0.0f), 223.0f);
        fx = fminf(fmaxf(fx, 0.0f), 223.0f);
        const float y0f = floorf(fy), x0f = floorf(fx);
        const float wy = fy - y0f,    wx = fx - x0f;
        const int y0 = (int)y0f, x0 = (int)x0f;
        const int y1 = min(y0 + 1, kHW - 1), x1 = min(x0 + 1, kHW - 1);
        const int r0 = (y0 - ybase) * kHW;
        const int r1 = (y1 - ybase) * kHW;
        const int oo = oy * kHW + ox;
#pragma unroll
        for (int c = 0; c < 3; ++c) {
            const float v00 = sm[c][r0 + x0];
            const float v01 = sm[c][r0 + x1];
            const float v10 = sm[c][r1 + x0];
            const float v11 = sm[c][r1 + x1];
            const float a0 = (1.0f - wx) * v00 + wx * v01;
            const float a1 = (1.0f - wx) * v10 + wx * v11;
            obase[c * kPlane + oo] = (1.0f - wy) * a0 + wy * a1;
        }
    }
}

extern "C" void kernel_launch(void* const* d_in, const int* in_sizes, int n_in,
                              void* d_out, int out_size, void* d_ws, size_t ws_size,
                              hipStream_t stream) {
    const float* img = (const float*)d_in[0];
    const float* uj  = (const float*)d_in[1];
    const float* ub  = (const float*)d_in[2];
    const float* uc  = (const float*)d_in[3];
    const float* us  = (const float*)d_in[4];
    const float* uh  = (const float*)d_in[5];
    const float* ucr = (const float*)d_in[6];
    const float* usc = (const float*)d_in[7];
    const float* ut  = (const float*)d_in[8];
    const float* ul  = (const float*)d_in[9];
    float* gray_sum  = (float*)d_ws;      // 256 floats
    float* out       = (float*)d_out;

    gray_mean_kernel<<<dim3(kB), 1024, 0, stream>>>(img, uj, ub, gray_sum);

    dim3 gridB(kHW / 4, kB, 1);
    aug_main_kernel<<<gridB, 256, 0, stream>>>(img, uj, ub, uc, us, uh,
                                               ucr, usc, ut, ul, gray_sum, out);
}

// Round 3
// 302.177 us; speedup vs baseline: 1.1111x; 1.0200x over previous
//
#include <hip/hip_runtime.h>

// ImageAugmentation: B=256, C=3, H=W=224, fp32.
// R3 structure:
//   gray_mean: 1 block (1024 thr) per image, float4 loads, plain store.
//   aug_main : 1 block (256 thr) per 8 output rows of one image.
//     crop-on : stage 9 jittered source rows in LDS via float4 loads
//               (jitter once per source px, 1.125x/output), bilinear from LDS,
//               float4 output stores.
//     crop-off: float4 load -> jitter -> float4 store (448 quads/block).
// Branches (jitter_on/crop_on) are uniform per block (blockIdx.y = image).
// floor() cliffs (crop params, fy/fx) computed with fp contract(off) to match
// the f32 reference op-for-op.

static constexpr int   kB      = 256;
static constexpr int   kHW     = 224;
static constexpr int   kHW4    = kHW / 4;      // 56 float4 per row
static constexpr int   kNPix   = kHW * kHW;    // 50176
static constexpr int   kPlane  = kNPix;
static constexpr int   kPlane4 = kNPix / 4;    // 12544
static constexpr int   kRows   = 8;            // output rows per block
static constexpr int   kSrcRows = kRows + 1;   // 9 source rows staged

__device__ __forceinline__ float clamp01(float x) {
    return fminf(fmaxf(x, 0.0f), 1.0f);
}

__device__ __forceinline__ float fast_rcp(float x) {
#if __has_builtin(__builtin_amdgcn_rcpf)
    return __builtin_amdgcn_rcpf(x);   // ~1 ulp; continuous effect, fine at 2e-2 tol
#else
    return 1.0f / x;
#endif
}

struct Px { float r, g, b; };

// Full color-jitter chain for one pixel. oc = (1-cf)*mean_gray per image.
__device__ __forceinline__ Px jitter_px(Px p, float bf, float cf, float sf,
                                        float hf, float oc) {
    float r = clamp01(bf * p.r);
    float g = clamp01(bf * p.g);
    float b = clamp01(bf * p.b);
    r = clamp01(cf * r + oc);
    g = clamp01(cf * g + oc);
    b = clamp01(cf * b + oc);
    float gray = 0.299f * r + 0.587f * g + 0.114f * b;
    float os = (1.0f - sf) * gray;
    r = clamp01(sf * r + os);
    g = clamp01(sf * g + os);
    b = clamp01(sf * b + os);
    float maxc = fmaxf(fmaxf(r, g), b);
    float minc = fminf(fminf(r, g), b);
    float v  = maxc;
    float cr = maxc - minc;
    bool  eqc = (cr == 0.0f);
    float s   = eqc ? 0.0f : cr * fast_rcp(maxc);
    float inv = eqc ? 1.0f : fast_rcp(cr);
    float rc = (maxc - r) * inv;
    float gc = (maxc - g) * inv;
    float bc = (maxc - b) * inv;
    float h = (maxc == r) ? (bc - gc)
            : (maxc == g) ? (2.0f + rc - bc)
                          : (4.0f + gc - rc);
    h = h * 0.16666667f + 1.0f;
    h = h - floorf(h);
    h = h + hf;
    h = h - floorf(h);
    float h6 = h * 6.0f;
    float fi = floorf(h6);
    float f  = h6 - fi;
    int   i  = ((int)fi) % 6;   // h6 in [0,6]; ==6 -> i=0,f=0 (matches ref)
    float pp = v * (1.0f - s);
    float qq = v * (1.0f - s * f);
    float tt = v * (1.0f - s * (1.0f - f));
    float r2 = (i == 1) ? qq : ((i == 2) || (i == 3)) ? pp : (i == 4) ? tt : v;
    float g2 = (i == 0) ? tt : ((i == 1) || (i == 2)) ? v  : (i == 3) ? qq : pp;
    float b2 = ((i == 0) || (i == 1)) ? pp : (i == 2) ? tt : (i == 5) ? qq : v;
    Px o;
    o.r = clamp01(r2);
    o.g = clamp01(g2);
    o.b = clamp01(b2);
    return o;
}

// jitter a float4-quad of 4 pixels (3 channels each), in place.
__device__ __forceinline__ void jitter_quad(float4& r4, float4& g4, float4& b4,
                                            float bf, float cf, float sf,
                                            float hf, float oc) {
    Px a0 = jitter_px({r4.x, g4.x, b4.x}, bf, cf, sf, hf, oc);
    Px a1 = jitter_px({r4.y, g4.y, b4.y}, bf, cf, sf, hf, oc);
    Px a2 = jitter_px({r4.z, g4.z, b4.z}, bf, cf, sf, hf, oc);
    Px a3 = jitter_px({r4.w, g4.w, b4.w}, bf, cf, sf, hf, oc);
    r4 = {a0.r, a1.r, a2.r, a3.r};
    g4 = {a0.g, a1.g, a2.g, a3.g};
    b4 = {a0.b, a1.b, a2.b, a3.b};
}

// Kernel A: per-image mean of grayscale(brightness(img)).
__global__ __launch_bounds__(1024)
void gray_mean_kernel(const float* __restrict__ img,
                      const float* __restrict__ u_jitter,
                      const float* __restrict__ u_bright,
                      float* __restrict__ gray_sum)
{
    const int b = blockIdx.x;
    if (u_jitter[b] >= 0.8f) return;   // mean unused for jitter-off images
    const float bf = 1.0f + (2.0f * u_bright[b] - 1.0f) * 0.2f;
    const float4* pr = (const float4*)(img + (size_t)b * 3 * kPlane);
    const float4* pg = pr + kPlane4;
    const float4* pb = pr + 2 * kPlane4;
    float acc = 0.0f;
    for (int i = threadIdx.x; i < kPlane4; i += 1024) {
        float4 r = pr[i], g = pg[i], bl = pb[i];
        acc += 0.299f * clamp01(bf * r.x) + 0.587f * clamp01(bf * g.x) + 0.114f * clamp01(bf * bl.x);
        acc += 0.299f * clamp01(bf * r.y) + 0.587f * clamp01(bf * g.y) + 0.114f * clamp01(bf * bl.y);
        acc += 0.299f * clamp01(bf * r.z) + 0.587f * clamp01(bf * g.z) + 0.114f * clamp01(bf * bl.z);
        acc += 0.299f * clamp01(bf * r.w) + 0.587f * clamp01(bf * g.w) + 0.114f * clamp01(bf * bl.w);
    }
#pragma unroll
    for (int off = 32; off > 0; off >>= 1)
        acc += __shfl_down(acc, off);
    __shared__ float red[16];
    const int lane = threadIdx.x & 63;
    const int w    = threadIdx.x >> 6;
    if (lane == 0) red[w] = acc;
    __syncthreads();
    if (threadIdx.x == 0) {
        float s = 0.0f;
#pragma unroll
        for (int k = 0; k < 16; ++k) s += red[k];
        gray_sum[b] = s;
    }
}

// Kernel B: one block = 8 output rows of one image.
__global__ __launch_bounds__(256)
void aug_main_kernel(const float* __restrict__ img,
                     const float* __restrict__ u_jitter,
                     const float* __restrict__ u_bright,
                     const float* __restrict__ u_contrast,
                     const float* __restrict__ u_sat,
                     const float* __restrict__ u_hue,
                     const float* __restrict__ u_crop,
                     const float* __restrict__ u_scale,
                     const float* __restrict__ u_top,
                     const float* __restrict__ u_left,
                     const float* __restrict__ gray_sum,
                     float* __restrict__ out)
{
    const int b   = blockIdx.y;
    const int oy0 = blockIdx.x * kRows;
    const int t   = threadIdx.x;

    const bool jitter_on = u_jitter[b] < 0.8f;
    const bool crop_on   = u_crop[b]   < 0.5f;

    float bf = 1.0f, cf = 1.0f, sf = 1.0f, hf = 0.0f, oc = 0.0f;
    if (jitter_on) {
        bf = 1.0f + (2.0f * u_bright[b]   - 1.0f) * 0.2f;
        cf = 1.0f + (2.0f * u_contrast[b] - 1.0f) * 0.2f;
        sf = 1.0f + (2.0f * u_sat[b]      - 1.0f) * 0.2f;
        hf = (2.0f * u_hue[b] - 1.0f) * 0.05f;
        const float mg = gray_sum[b] * (1.0f / (float)kNPix);
        oc = (1.0f - cf) * mg;
    }

    const float*  base  = img + (size_t)b * 3 * kPlane;
    float*        obase = out + (size_t)b * 3 * kPlane;
    const float4* p4    = (const float4*)base;
    float4*       o4    = (float4*)obase;

    if (!crop_on) {
        // 8 rows = 448 float4 per plane; process pixel-quads across 3 planes.
        for (int q = t; q < kRows * kHW4; q += 256) {
            const int f4 = oy0 * kHW4 + q;
            float4 r4 = p4[f4];
            float4 g4 = p4[f4 + kPlane4];
            float4 b4 = p4[f4 + 2 * kPlane4];
            if (jitter_on) jitter_quad(r4, g4, b4, bf, cf, sf, hf, oc);
            o4[f4]               = r4;
            o4[f4 + kPlane4]     = g4;
            o4[f4 + 2 * kPlane4] = b4;
        }
        return;
    }

    // ---- crop path ----
    float ch, top, left;
    {
#pragma clang fp contract(off)
        // floor() cliffs must match reference f32 op-for-op (no fma contraction)
        float scale = 0.85f + 0.15f * u_scale[b];
        ch = floorf(224.0f * scale);             // cw == ch (H == W)
        float rem = (224.0f - ch) + 1.0f;
        top  = fminf(fmaxf(floorf(u_top[b]  * rem), 0.0f), 224.0f - ch);
        left = fminf(fmaxf(floorf(u_left[b] * rem), 0.0f), 224.0f - ch);
    }

    // Block-uniform source window: rows [ybase, ybase+8] cover all taps of
    // output rows oy0..oy0+7 (source step ch/224 <= 1).
    int ybase;
    {
#pragma clang fp contract(off)
        float fy0 = top + ((float)oy0 + 0.5f) * ch / 224.0f - 0.5f;
        fy0 = fminf(fmaxf(fy0, 0.0f), 223.0f);
        ybase = (int)floorf(fy0);
    }
    ybase = min(ybase, kHW - kSrcRows);   // ensure ybase+8 <= 223

    __shared__ float sm[3][kSrcRows * kHW];   // 3*9*224*4 = 24.2 KB

    // Stage + jitter 9 source rows: 504 pixel-quads, float4 loads,
    // ds_write_b128 stores (conflict-free consecutive layout).
    for (int q = t; q < kSrcRows * kHW4; q += 256) {
        const int r  = q / kHW4;
        const int xq = q - r * kHW4;
        const int gi = (ybase + r) * kHW4 + xq;
        float4 r4 = p4[gi];
        float4 g4 = p4[gi + kPlane4];
        float4 b4 = p4[gi + 2 * kPlane4];
        if (jitter_on) jitter_quad(r4, g4, b4, bf, cf, sf, hf, oc);
        const int so = r * kHW + xq * 4;
        *(float4*)&sm[0][so] = r4;
        *(float4*)&sm[1][so] = g4;
        *(float4*)&sm[2][so] = b4;
    }
    __syncthreads();

    // 8 rows x 56 quads = 448 output float4 per plane; bilinear from LDS.
    for (int q = t; q < kRows * kHW4; q += 256) {
        const int dy = q / kHW4;
        const int xq = q - dy * kHW4;
        const int oy = oy0 + dy;
        float fy;
        {
#pragma clang fp contract(off)
            fy = top + ((float)oy + 0.5f) * ch / 224.0f - 0.5f;
        }
        fy = fminf(fmaxf(fy, 0.0f), 223.0f);
        const float y0f = floorf(fy);
        const float wy  = fy - y0f;
        const int   y0  = (int)y0f;
        const int   y1  = min(y0 + 1, kHW - 1);
        const int   r0  = (y0 - ybase) * kHW;
        const int   r1  = (y1 - ybase) * kHW;

        float4 res[3];
#pragma unroll
        for (int j = 0; j < 4; ++j) {
            const int ox = xq * 4 + j;
            float fx;
            {
#pragma clang fp contract(off)
                fx = left + ((float)ox + 0.5f) * ch / 224.0f - 0.5f;
            }
            fx = fminf(fmaxf(fx, 0.0f), 223.0f);
            const float x0f = floorf(fx);
            const float wx  = fx - x0f;
            const int   x0  = (int)x0f;
            const int   x1  = min(x0 + 1, kHW - 1);
#pragma unroll
            for (int c = 0; c < 3; ++c) {
                const float v00 = sm[c][r0 + x0];
                const float v01 = sm[c][r0 + x1];
                const float v10 = sm[c][r1 + x0];
                const float v11 = sm[c][r1 + x1];
                const float a0 = (1.0f - wx) * v00 + wx * v01;
                const float a1 = (1.0f - wx) * v10 + wx * v11;
                ((float*)&res[c])[j] = (1.0f - wy) * a0 + wy * a1;
            }
        }
        const int oo = oy * kHW4 + xq;
        o4[oo]               = res[0];
        o4[oo + kPlane4]     = res[1];
        o4[oo + 2 * kPlane4] = res[2];
    }
}

extern "C" void kernel_launch(void* const* d_in, const int* in_sizes, int n_in,
                              void* d_out, int out_size, void* d_ws, size_t ws_size,
                              hipStream_t stream) {
    const float* img = (const float*)d_in[0];
    const float* uj  = (const float*)d_in[1];
    const float* ub  = (const float*)d_in[2];
    const float* uc  = (const float*)d_in[3];
    const float* us  = (const float*)d_in[4];
    const float* uh  = (const float*)d_in[5];
    const float* ucr = (const float*)d_in[6];
    const float* usc = (const float*)d_in[7];
    const float* ut  = (const float*)d_in[8];
    const float* ul  = (const float*)d_in[9];
    float* gray_sum  = (float*)d_ws;      // 256 floats
    float* out       = (float*)d_out;

    gray_mean_kernel<<<dim3(kB), 1024, 0, stream>>>(img, uj, ub, gray_sum);

    dim3 gridB(kHW / kRows, kB, 1);
    aug_main_kernel<<<gridB, 256, 0, stream>>>(img, uj, ub, uc, us, uh,
                                               ucr, usc, ut, ul, gray_sum, out);
}